// Round 8
// baseline (3362.941 us; speedup 1.0000x reference)
//
#include <hip/hip_runtime.h>
#include <hip/hip_bf16.h>

typedef short short8_v __attribute__((ext_vector_type(8)));
typedef float f32x4 __attribute__((ext_vector_type(4)));
typedef unsigned long long u64x2_v __attribute__((ext_vector_type(2)));

#define QC 576  // padded qkva column stride: q[0,256) val[256,512) act[512,556) pad[556,576)

// fragment-swizzled layout: element (r,k) of an [R][K] operand ->
// tile (r/16, k/32), lane = (r%16) + 16*((k%32)/8), elem = k%8
__device__ __forceinline__ size_t swz_e(int r, int k, int KC) {
  return ((size_t)((r >> 4) * KC + (k >> 5)) * 64 + (r & 15) + (((k >> 3) & 3) << 4)) * 8 + (k & 7);
}

__device__ __forceinline__ float wave_sum(float v) {
#pragma unroll
  for (int off = 32; off > 0; off >>= 1) v += __shfl_xor(v, off);
  return v;
}

__device__ __forceinline__ float sigf(float x) { return 1.f / (1.f + __expf(-x)); }
// fast tanh via __expf: exact at saturation
__device__ __forceinline__ float tfast(float x) {
  float e = __expf(2.f * x);
  return 1.f - 2.f / (e + 1.f);
}

// relaxed agent-scope atomics: L1-bypassing, coherent across XCDs
template <typename T>
__device__ __forceinline__ T ald(const T* p) {
  return __hip_atomic_load(p, __ATOMIC_RELAXED, __HIP_MEMORY_SCOPE_AGENT);
}
template <typename T>
__device__ __forceinline__ void ast(T* p, T v) {
  __hip_atomic_store(p, v, __ATOMIC_RELAXED, __HIP_MEMORY_SCOPE_AGENT);
}

// ---------------- prologue kernels (once per call) ----------------

__global__ void prep_weights(const float* __restrict__ W_ih, const float* __restrict__ W_hh,
                             __hip_bfloat16* __restrict__ Wcat) {
  int idx = blockIdx.x * blockDim.x + threadIdx.x;  // 1024*512
  if (idx >= 1024 * 512) return;
  int jj = idx >> 9, k = idx & 511;
  int chunk = jj >> 6, gate = (jj >> 4) & 3, r = jj & 15;
  int j = gate * 256 + chunk * 16 + r;
  float v = (k < 256) ? W_ih[j * 256 + k] : W_hh[j * 256 + (k - 256)];
  Wcat[swz_e(jj, k, 16)] = __float2bfloat16(v);
}

__global__ void prep_wq(const float* __restrict__ Wq_w, const float* __restrict__ Wq_b,
                        __hip_bfloat16* __restrict__ Wq, float* __restrict__ biasq) {
  int idx = blockIdx.x * blockDim.x + threadIdx.x;  // 576*256
  if (idx >= 576 * 256) return;
  int n = idx >> 8, k = idx & 255;
  int orig = (n < 256) ? n : (n < 556 ? n + 256 : -1);
  float v = (orig >= 0) ? Wq_w[orig * 256 + k] : 0.f;
  Wq[swz_e(n, k, 8)] = __float2bfloat16(v);
  if (k == 0) biasq[n] = (orig >= 0) ? Wq_b[orig] : 0.f;
}

__global__ void prep_tgt(const float* __restrict__ tgt, __hip_bfloat16* __restrict__ tswz) {
  for (size_t idx = (size_t)blockIdx.x * blockDim.x + threadIdx.x; idx < (size_t)128 * 131072;
       idx += (size_t)gridDim.x * blockDim.x) {
    int t = (int)(idx >> 17);
    int rem = (int)(idx & 131071);
    int b = rem >> 8, k = rem & 255;
    tswz[(size_t)t * 131072 + swz_e(b, k, 8)] = __float2bfloat16(tgt[idx]);
  }
}

__global__ void reset_bars(unsigned* __restrict__ bars) {
  int i = blockIdx.x * blockDim.x + threadIdx.x;
  if (i < 2048) bars[i] = 0u;
}

// ---------------- persistent kernel: wave-specialized ----------------
// grid 256 x 512 (1 block/CU). Group m (0..31) = 8 blocks {m + 32*cgrp}, cgrp 0..7.
// Waves 0-3: TAPE — 2 pairs each (q = 2w+u: b = 16m+2cgrp+(q>>2), tp = q&3).
// Waves 4-7: GEMM — wave gw computes gate gw for both 16-col chunks (tiles 8cgrp+4t+gw),
//   one qkva tile qst+gw (+ qst+4 for gw==0 when qcnt==5), epilogue on threads 256-511
//   (2 h-cols each: jh = 32cgrp + 16u + ecol). h(p-1) held in registers (aH, agent loads).
// Phase p: [tape row pass(s=p-2) || gates(p)] sync [tape col pass || epilogue+qkva(p-1)
//   + drain + gemm-gated arrive] sync [tid0 group poll] sync.
// LDS (floats): Tc 8*4096 @0 ; WS 8*128 @32768 ; QN 8*64 @33792 ; gbuf [2][4][16][16] @34304 ;
//   gctr @36352 ; total 36416 f = 145664 B
#define DYN_LDS 145664

__global__ __launch_bounds__(512, 2) void persist(
    const short8_v* __restrict__ tswz, const short8_v* __restrict__ Wcat,
    const short8_v* __restrict__ Wq, const float* __restrict__ biasq,
    const float* __restrict__ b_ih, const float* __restrict__ b_hh,
    unsigned short* __restrict__ hG,  // 2 x 131072 bf16 (frag-swizzled), dbuf
    float* __restrict__ qkva,         // 2 x 512*QC f32, dbuf
    float* __restrict__ out, const float* __restrict__ src, unsigned* __restrict__ bars) {
  extern __shared__ float lds[];
  const int tid = threadIdx.x;
  const int w = tid >> 6, lane = tid & 63;
  const int m = (int)blockIdx.x & 31, cgrp = (int)blockIdx.x >> 5;  // cgrp 0..7
  unsigned* grpbar = bars + m * 64;
  unsigned* gctr = (unsigned*)(lds + 36352);
  float* gbuf = lds + 34304;  // [2 chunk][4 gate][16 row][16 col]

  const int g = lane >> 4, c4 = lane & 15;
  const bool isTape = (w < 4);
  const int gw = w & 3;  // gemm wave id (gate) when w>=4

  if (tid == 0) *gctr = 0u;
  bool bar_ok = true;

  // ---- tape state (waves 0-3) ----
  float wp[2], rp[2], wpPrev[2];
  f32x4 dvp4[2];
  int bq[2], tpq[2];
  if (isTape) {
#pragma unroll
    for (int u = 0; u < 2; ++u) {
      int q = 2 * w + u;
      bq[u] = 16 * m + 2 * cgrp + (q >> 2);
      tpq[u] = q & 3;
      f32x4* Tc = (f32x4*)lds + (size_t)q * 1024;
#pragma unroll
      for (int i = 0; i < 16; ++i) {
        int row = i * 4 + g;
        f32x4 v = *(const f32x4*)(src + (size_t)row * 131072 + bq[u] * 256 + tpq[u] * 64 + c4 * 4);
        Tc[row * 16 + (c4 ^ (row & 15))] = v;
      }
      wp[u] = (lane == 0) ? 1.f : 0.f;
      rp[u] = wp[u];
      wpPrev[u] = 0.f;
      dvp4[u] = (f32x4){0.f, 0.f, 0.f, 0.f};
    }
  }

  // ---- gemm state (waves 4-7) ----
  const int erow = (tid & 255) >> 4, ecol = tid & 15;
  float c_reg[2] = {0.f, 0.f};
  float bIa[2], bFa[2], bGa[2], bOa[2];
  unsigned hIdx32[2];
  int qtile[2] = {0, 0}, nqt = 0, n0[2] = {0, 0};
  float bqv[2] = {0.f, 0.f};
  if (!isTape) {
#pragma unroll
    for (int u = 0; u < 2; ++u) {
      int jh = 32 * cgrp + 16 * u + ecol;
      bIa[u] = b_ih[jh] + b_hh[jh];
      bFa[u] = b_ih[256 + jh] + b_hh[256 + jh];
      bGa[u] = b_ih[512 + jh] + b_hh[512 + jh];
      bOa[u] = b_ih[768 + jh] + b_hh[768 + jh];
      hIdx32[u] =
          (unsigned)(((m * 8 + (jh >> 5)) * 64 + erow + 16 * ((jh >> 3) & 3)) * 4 + ((jh >> 1) & 3));
    }
    const int qcnt = (cgrp < 4) ? 5 : 4;
    const int qst = (cgrp < 4) ? 5 * cgrp : 20 + 4 * (cgrp - 4);
    qtile[0] = qst + gw;
    nqt = 1;
    if (gw == 0 && qcnt == 5) {
      qtile[1] = qst + 4;
      nqt = 2;
    }
#pragma unroll
    for (int u = 0; u < 2; ++u) {
      int qt = (u < nqt) ? qtile[u] : qtile[0];
      n0[u] = qt * 16 + (lane & 15);
      bqv[u] = biasq[n0[u]];
    }
  }
  __syncthreads();  // gctr init + Tc init complete

#pragma unroll 1
  for (int p = 0; p <= 129; ++p) {
    const int hrd = (p + 1) & 1, hwr = p & 1;
    const int s = p - 2;  // tape step

    // ---- issue loads ----
    float a_[2][11];
    f32x4 q4[2], val4[2];
    short8_v aF[8], aH[8];
    float rd[2][4], wd[2][4];
    if (isTape) {
      if (s >= 0) {
#pragma unroll
        for (int u = 0; u < 2; ++u) {
          const float* qrow = qkva + (size_t)(s & 1) * (512 * QC) + (size_t)bq[u] * QC;
#pragma unroll
          for (int j = 0; j < 11; ++j) a_[u][j] = ald(qrow + 512 + tpq[u] * 11 + j);
          unsigned long long u0 = ald((const unsigned long long*)(qrow + tpq[u] * 64 + c4 * 4));
          unsigned long long u1 = ald((const unsigned long long*)(qrow + tpq[u] * 64 + c4 * 4 + 2));
          unsigned long long v0 = ald((const unsigned long long*)(qrow + 256 + tpq[u] * 64 + c4 * 4));
          unsigned long long v1 =
              ald((const unsigned long long*)(qrow + 256 + tpq[u] * 64 + c4 * 4 + 2));
          float2 qa = __builtin_bit_cast(float2, u0), qb = __builtin_bit_cast(float2, u1);
          float2 va = __builtin_bit_cast(float2, v0), vb = __builtin_bit_cast(float2, v1);
          q4[u] = (f32x4){qa.x, qa.y, qb.x, qb.y};
          val4[u] = (f32x4){va.x, va.y, vb.x, vb.y};
        }
      }
    } else {
      if (p < 128) {
        const short8_v* xg = tswz + (size_t)p * 16384;
#pragma unroll
        for (int kc = 0; kc < 8; ++kc) aF[kc] = xg[(m * 8 + kc) * 64 + lane];
      }
      if (p >= 1 && p <= 128) {
        const unsigned long long* hsrc = (const unsigned long long*)(hG + (size_t)hrd * 131072);
#pragma unroll
        for (int kc = 0; kc < 8; ++kc) {
          size_t bi = ((size_t)(m * 8 + kc) * 64 + lane) * 2;
          u64x2_v t2;
          t2.x = ald(hsrc + bi);
          t2.y = ald(hsrc + bi + 1);
          aH[kc] = __builtin_bit_cast(short8_v, t2);
        }
      }
    }

    // ---- segment 1: tape row pass || gates MFMA ----
    if (isTape) {
      if (s >= 0) {
#pragma unroll
        for (int u = 0; u < 2; ++u) {
          float m1 = fmaxf(fmaxf(a_[u][0], a_[u][1]), fmaxf(a_[u][2], a_[u][3]));
          float e0 = __expf(a_[u][0] - m1), e1 = __expf(a_[u][1] - m1), e2 = __expf(a_[u][2] - m1),
                e3 = __expf(a_[u][3] - m1);
          float inv = 1.f / (e0 + e1 + e2 + e3);
          rd[u][0] = e0 * inv; rd[u][1] = e1 * inv; rd[u][2] = e2 * inv; rd[u][3] = e3 * inv;
          float m2 = fmaxf(fmaxf(a_[u][4], a_[u][5]), fmaxf(a_[u][6], a_[u][7]));
          float f0 = __expf(a_[u][4] - m2), f1 = __expf(a_[u][5] - m2), f2 = __expf(a_[u][6] - m2),
                f3 = __expf(a_[u][7] - m2);
          float inv2 = 1.f / (f0 + f1 + f2 + f3);
          wd[u][0] = f0 * inv2; wd[u][1] = f1 * inv2; wd[u][2] = f2 * inv2; wd[u][3] = f3 * inv2;
          float rwe0 = sigf(a_[u][8]), rwe1 = sigf(a_[u][9]), rwe2 = sigf(a_[u][10]);
          // qn: reduce within 16-lane c4 group (all g copies identical)
          float ss = q4[u][0] * q4[u][0] + q4[u][1] * q4[u][1] + q4[u][2] * q4[u][2] +
                     q4[u][3] * q4[u][3];
#pragma unroll
          for (int off = 1; off < 16; off <<= 1) ss += __shfl_xor(ss, off);
          float qninv = 1.f / fmaxf(sqrtf(ss), 1e-12f);
          f32x4 qn4 = q4[u] * qninv;
          const int q = 2 * w + u;
          float* WSq = lds + 32768 + q * 128;
          float* QNq = lds + 33792 + q * 64;
          *(float2*)&WSq[lane * 2] = make_float2(wp[u], rp[u] * rwe0);
          if (g == 0) *(f32x4*)&QNq[c4 * 4] = qn4;
          f32x4* Tc = (f32x4*)lds + (size_t)q * 1024;
          f32x4 oa = {0.f, 0.f, 0.f, 0.f}, ra = oa;
#pragma unroll
          for (int i = 0; i < 16; ++i) {
            int row = i * 4 + g;
            float wO = __shfl(wpPrev[u], row);
            float2 wrN = *(const float2*)&WSq[row * 2];
            int ti = row * 16 + (c4 ^ (row & 15));
            f32x4 v = Tc[ti];
            v += wO * dvp4[u];
            Tc[ti] = v;
            oa += wrN.x * v;
            ra += wrN.y * v;
          }
#pragma unroll
          for (int off = 16; off <= 32; off <<= 1) {
            f32x4 t;
            t[0] = __shfl_xor(oa[0], off); t[1] = __shfl_xor(oa[1], off);
            t[2] = __shfl_xor(oa[2], off); t[3] = __shfl_xor(oa[3], off);
            oa += t;
            t[0] = __shfl_xor(ra[0], off); t[1] = __shfl_xor(ra[1], off);
            t[2] = __shfl_xor(ra[2], off); t[3] = __shfl_xor(ra[3], off);
            ra += t;
          }
          dvp4[u] = val4[u] * rwe1 - oa * rwe2;
          if (g == 0)
            *(f32x4*)(out + (size_t)s * 131072 + bq[u] * 256 + tpq[u] * 64 + c4 * 4) = ra;
        }
      }
    } else {
      if (p < 128) {
#pragma unroll
        for (int t = 0; t < 2; ++t) {
          const int T = 8 * cgrp + 4 * t + gw;  // gate=gw, chunk=2cgrp+t
          f32x4 acc = {0.f, 0.f, 0.f, 0.f};
#pragma unroll
          for (int kc = 0; kc < 8; ++kc)
            acc = __builtin_amdgcn_mfma_f32_16x16x32_bf16(aF[kc], Wcat[(T * 16 + kc) * 64 + lane],
                                                          acc, 0, 0, 0);
          if (p > 0) {
#pragma unroll
            for (int kc = 8; kc < 16; ++kc)
              acc = __builtin_amdgcn_mfma_f32_16x16x32_bf16(
                  aH[kc - 8], Wcat[(T * 16 + kc) * 64 + lane], acc, 0, 0, 0);
          }
#pragma unroll
          for (int r = 0; r < 4; ++r)
            gbuf[((t * 4 + gw) * 16 + ((lane >> 4) * 4 + r)) * 16 + (lane & 15)] = acc[r];
        }
      }
    }
    __syncthreads();  // gbuf ready

    // ---- segment 2: tape col pass || epilogue + qkva + arrive ----
    if (isTape) {
      if (s >= 0) {
#pragma unroll
        for (int u = 0; u < 2; ++u) {
          const int q = 2 * w + u;
          f32x4* Tc = (f32x4*)lds + (size_t)q * 1024;
          float* QNq = lds + 33792 + q * 64;
          float jq = 0.f;
#pragma unroll
          for (int j = 0; j < 16; ++j) {
            f32x4 v = Tc[lane * 16 + (j ^ (lane & 15))];
            f32x4 qv = *(const f32x4*)&QNq[j * 4];
            jq += v[0] * qv[0] + v[1] * qv[1] + v[2] * qv[2] + v[3] * qv[3];
          }
          float jsum = wave_sum(jq * jq);
          float jp = jq / fmaxf(sqrtf(jsum), 1e-12f);
          float next_w = __shfl(wp[u], (lane + 63) & 63);
          float prev_w = __shfl(wp[u], (lane + 1) & 63);
          float next_r = __shfl(rp[u], (lane + 63) & 63);
          float prev_r = __shfl(rp[u], (lane + 1) & 63);
          wpPrev[u] = wp[u];
          wp[u] = prev_w * wd[u][0] + wp[u] * wd[u][1] + next_w * wd[u][2] + jp * wd[u][3];
          rp[u] = prev_r * rd[u][0] + rp[u] * rd[u][1] + next_r * rd[u][2] + jp * rd[u][3];
        }
      }
    } else {
      if (p < 128) {
#pragma unroll
        for (int u = 0; u < 2; ++u) {
          float gi = gbuf[((u * 4 + 0) * 16 + erow) * 16 + ecol] + bIa[u];
          float gf = gbuf[((u * 4 + 1) * 16 + erow) * 16 + ecol] + bFa[u];
          float gg = gbuf[((u * 4 + 2) * 16 + erow) * 16 + ecol] + bGa[u];
          float go = gbuf[((u * 4 + 3) * 16 + erow) * 16 + ecol] + bOa[u];
          float cc = sigf(gf) * c_reg[u] + sigf(gi) * tfast(gg);
          c_reg[u] = cc;
          float hh = sigf(go) * tfast(cc);
          __hip_bfloat16 hb16 = __float2bfloat16(hh);
          unsigned own = (unsigned)(*(unsigned short*)&hb16);
          unsigned other = (unsigned)__shfl_xor((int)own, 1) & 0xFFFFu;
          if ((ecol & 1) == 0) {
            unsigned pack = (other << 16) | own;
            ast((unsigned*)(hG + (size_t)hwr * 131072) + hIdx32[u], pack);
          }
        }
      }
      if (p >= 1 && p <= 128) {
        float* qw = qkva + (size_t)((p - 1) & 1) * (512 * QC);
#pragma unroll
        for (int u = 0; u < 2; ++u) {
          if (u < nqt) {
            f32x4 qa = {0.f, 0.f, 0.f, 0.f};
#pragma unroll
            for (int kc = 0; kc < 8; ++kc)
              qa = __builtin_amdgcn_mfma_f32_16x16x32_bf16(
                  aH[kc], Wq[(qtile[u] * 8 + kc) * 64 + lane], qa, 0, 0, 0);
#pragma unroll
            for (int r = 0; r < 4; ++r)
              ast(&qw[(size_t)(16 * m + (lane >> 4) * 4 + r) * QC + n0[u]], qa[r] + bqv[u]);
          }
        }
      }
      // drain own h/qkva stores, then gemm-gated group arrival
      asm volatile("s_waitcnt vmcnt(0)" ::: "memory");
      if (p < 129) {
        if (lane == 0)
          __hip_atomic_fetch_add(gctr, 1u, __ATOMIC_RELAXED, __HIP_MEMORY_SCOPE_WORKGROUP);
        if (tid == 256) {
          unsigned tgt4 = 4u * (unsigned)(p + 1);
          while (__hip_atomic_load(gctr, __ATOMIC_RELAXED, __HIP_MEMORY_SCOPE_WORKGROUP) < tgt4)
            __builtin_amdgcn_s_sleep(1);
          __hip_atomic_fetch_add(grpbar, 1u, __ATOMIC_RELAXED, __HIP_MEMORY_SCOPE_AGENT);
        }
      }
    }
    __syncthreads();
    // ---- group barrier poll (tape tail + other roles already hid most skew) ----
    if (p < 129) {
      if (tid == 0) {
        unsigned target = 8u * (unsigned)(p + 1);
        if (bar_ok) {
          long long t0 = (long long)__builtin_amdgcn_s_memrealtime();
          while (ald(grpbar) < target) {
            __builtin_amdgcn_s_sleep(8);
            if ((long long)__builtin_amdgcn_s_memrealtime() - t0 > 100000000LL) {
              bar_ok = false;  // ~1s escape valve: never hang
              break;
            }
          }
        }
        asm volatile("" ::: "memory");
      }
      __syncthreads();
    }
  }
}

// ---------------- host ----------------

extern "C" void kernel_launch(void* const* d_in, const int* in_sizes, int n_in, void* d_out,
                              int out_size, void* d_ws, size_t ws_size, hipStream_t stream) {
  const float* tgt = (const float*)d_in[0];
  const float* src = (const float*)d_in[1];
  const float* W_ih = (const float*)d_in[2];
  const float* W_hh = (const float*)d_in[3];
  const float* b_ih = (const float*)d_in[4];
  const float* b_hh = (const float*)d_in[5];
  const float* Wq_w = (const float*)d_in[6];
  const float* Wq_b = (const float*)d_in[7];
  float* out = (float*)d_out;

  char* ws = (char*)d_ws;
  size_t off = 0;
  auto alloc = [&](size_t bytes) -> void* {
    void* p = ws + off;
    off = (off + bytes + 255) & ~(size_t)255;
    return p;
  };
  unsigned* bars = (unsigned*)alloc(2048 * 4);
  float* qkva = (float*)alloc((size_t)2 * 512 * QC * 4);
  unsigned short* hG = (unsigned short*)alloc((size_t)2 * 131072 * 2);
  __hip_bfloat16* Wcat = (__hip_bfloat16*)alloc((size_t)1024 * 512 * 2);
  __hip_bfloat16* Wq = (__hip_bfloat16*)alloc((size_t)576 * 256 * 2);
  float* biasq = (float*)alloc((size_t)576 * 4);
  __hip_bfloat16* tswz = (__hip_bfloat16*)alloc((size_t)128 * 131072 * 2);

  reset_bars<<<8, 256, 0, stream>>>(bars);
  prep_weights<<<2048, 256, 0, stream>>>(W_ih, W_hh, Wcat);
  prep_wq<<<576, 256, 0, stream>>>(Wq_w, Wq_b, Wq, biasq);
  prep_tgt<<<8192, 256, 0, stream>>>(tgt, tswz);

  hipFuncSetAttribute((const void*)persist, hipFuncAttributeMaxDynamicSharedMemorySize, DYN_LDS);

  persist<<<dim3(256), dim3(512), DYN_LDS, stream>>>(
      (const short8_v*)tswz, (const short8_v*)Wcat, (const short8_v*)Wq, biasq, b_ih, b_hh, hG,
      qkva, out, src, bars);
}

// Round 12
// 1259.195 us; speedup vs baseline: 2.6707x; 2.6707x over previous
//
#include <hip/hip_runtime.h>
#include <hip/hip_bf16.h>

typedef short short8_v __attribute__((ext_vector_type(8)));
typedef float f32x4 __attribute__((ext_vector_type(4)));

#define QC 576  // padded qkva column stride: q[0,256) val[256,512) act[512,556) pad[556,576)

// fragment-swizzled layout: element (r,k) of an [R][K] operand ->
// tile (r/16, k/32), lane = (r%16) + 16*((k%32)/8), elem = k%8
__device__ __forceinline__ size_t swz_e(int r, int k, int KC) {
  return ((size_t)((r >> 4) * KC + (k >> 5)) * 64 + (r & 15) + (((k >> 3) & 3) << 4)) * 8 + (k & 7);
}

__device__ __forceinline__ float wave_sum(float v) {
#pragma unroll
  for (int off = 32; off > 0; off >>= 1) v += __shfl_xor(v, off);
  return v;
}

__device__ __forceinline__ float sigf(float x) { return 1.f / (1.f + __expf(-x)); }
// fast tanh via __expf: exact at saturation
__device__ __forceinline__ float tfast(float x) {
  float e = __expf(2.f * x);
  return 1.f - 2.f / (e + 1.f);
}

// relaxed agent-scope atomics: L1-bypassing, coherent across XCDs
template <typename T>
__device__ __forceinline__ T ald(const T* p) {
  return __hip_atomic_load(p, __ATOMIC_RELAXED, __HIP_MEMORY_SCOPE_AGENT);
}
template <typename T>
__device__ __forceinline__ void ast(T* p, T v) {
  __hip_atomic_store(p, v, __ATOMIC_RELAXED, __HIP_MEMORY_SCOPE_AGENT);
}

// ---------------- prologue kernels (once per call) ----------------

__global__ void prep_weights(const float* __restrict__ W_ih, const float* __restrict__ W_hh,
                             __hip_bfloat16* __restrict__ Wcat) {
  int idx = blockIdx.x * blockDim.x + threadIdx.x;  // 1024*512
  if (idx >= 1024 * 512) return;
  int jj = idx >> 9, k = idx & 511;
  int chunk = jj >> 6, gate = (jj >> 4) & 3, r = jj & 15;
  int j = gate * 256 + chunk * 16 + r;
  float v = (k < 256) ? W_ih[j * 256 + k] : W_hh[j * 256 + (k - 256)];
  Wcat[swz_e(jj, k, 16)] = __float2bfloat16(v);
}

__global__ void prep_wq(const float* __restrict__ Wq_w, const float* __restrict__ Wq_b,
                        __hip_bfloat16* __restrict__ Wq, float* __restrict__ biasq) {
  int idx = blockIdx.x * blockDim.x + threadIdx.x;  // 576*256
  if (idx >= 576 * 256) return;
  int n = idx >> 8, k = idx & 255;
  int orig = (n < 256) ? n : (n < 556 ? n + 256 : -1);
  float v = (orig >= 0) ? Wq_w[orig * 256 + k] : 0.f;
  Wq[swz_e(n, k, 8)] = __float2bfloat16(v);
  if (k == 0) biasq[n] = (orig >= 0) ? Wq_b[orig] : 0.f;
}

__global__ void prep_tgt(const float* __restrict__ tgt, __hip_bfloat16* __restrict__ tswz) {
  for (size_t idx = (size_t)blockIdx.x * blockDim.x + threadIdx.x; idx < (size_t)128 * 131072;
       idx += (size_t)gridDim.x * blockDim.x) {
    int t = (int)(idx >> 17);
    int rem = (int)(idx & 131071);
    int b = rem >> 8, k = rem & 255;
    tswz[(size_t)t * 131072 + swz_e(b, k, 8)] = __float2bfloat16(tgt[idx]);
  }
}

__global__ void reset_bars(unsigned* __restrict__ bars) {
  int i = blockIdx.x * blockDim.x + threadIdx.x;
  if (i < 2048) bars[i] = 0u;
}

// ---------------- persistent cooperative kernel (round-4 champion + aF prefetch) ----------------
// grid = 256 blocks x 512 threads. Group g = m (0..31) = blocks {m + 32*cgrp}.
// Block (m,cgrp): owns 8 tape pairs (b = 16m + 2*cgrp + {0,1}, tp 0..3, one per wave),
// computes gates slice (rows 16m..16m+16, h-cols [32*cgrp, 32*cgrp+32) all 4 gates) and
// qkva tiles [qst, qst+qcnt) for rows 16m.
// Phase p: gates(p)+LSTM -> h(p) || qkva(p-1) || arrive || aF(p+1) prefetch || tape(p-2) || poll.
// LDS (floats): tape 8*[64 rows][16 chunks]f32x4 XOR-swizzled @0 (32768 f) ;
//   stash 8*384 @32768 (wsrs[2][64]f2, qn_s[64], dv_s[64]) ; gbuf 2048 @35840 ;
//   hstage 2048 @37888 ; total 39936 f = 159744 B
#define DYN_LDS 159744

__global__ __launch_bounds__(512, 2) void persist(
    const short8_v* __restrict__ tswz, const short8_v* __restrict__ Wcat,
    const short8_v* __restrict__ Wq, const float* __restrict__ biasq,
    const float* __restrict__ b_ih, const float* __restrict__ b_hh,
    unsigned short* __restrict__ hG,  // 2 x 131072 bf16 (frag-swizzled), dbuf
    float* __restrict__ qkva,         // 2 x 512*QC f32, dbuf
    float* __restrict__ out, const float* __restrict__ src, unsigned* __restrict__ bars) {
  extern __shared__ float lds[];
  const int tid = threadIdx.x;
  const int w = tid >> 6, lane = tid & 63;
  const int m = blockIdx.x & 31, cgrp = blockIdx.x >> 5;
  unsigned* grpbar = bars + m * 64;

  f32x4* Tc = (f32x4*)lds + (size_t)w * 1024;  // tape [64][16] chunks, phys ch = c4^(row&15)
  float* S = lds + 32768 + w * 384;            // wsrs[2][128] ; qn_s@256 ; dv_s@320
  float* gbuf = lds + 35840;                   // [2][4][16][16]
  unsigned long long* hstage_u64 = (unsigned long long*)(lds + 37888);
  const short8_v* hstage_s8 = (const short8_v*)(lds + 37888);

  const int g = lane >> 4, c4 = lane & 15;

  // ---- tape pair identity + init ----
  const int b = 16 * m + 2 * cgrp + (w >> 2);
  const int tp = w & 3;
#pragma unroll
  for (int i = 0; i < 16; ++i) {
    int row = i * 4 + g;
    f32x4 v = *(const f32x4*)(src + (size_t)row * 131072 + b * 256 + tp * 64 + c4 * 4);
    Tc[row * 16 + (c4 ^ (row & 15))] = v;
  }
#pragma unroll
  for (int k = 0; k < 6; ++k) S[k * 64 + lane] = 0.f;  // zero stash (wsrs both, qn, dv)
  float rp = (lane == 0) ? 1.f : 0.f, wp = rp;

  // ---- epilogue roles: thread -> one h value (row = tid>>5, colLocal = tid&31) ----
  const int erow = tid >> 5, ecol = tid & 31;
  const int jh = 32 * cgrp + ecol;
  const float bI = b_ih[jh] + b_hh[jh];
  const float bF = b_ih[256 + jh] + b_hh[256 + jh];
  const float bG_ = b_ih[512 + jh] + b_hh[512 + jh];
  const float bO = b_ih[768 + jh] + b_hh[768 + jh];
  float c_reg = 0.f;
  const unsigned hIdx32 =
      (unsigned)(((m * 8 + cgrp) * 64 + erow + 16 * (ecol >> 3)) * 4 + ((ecol >> 1) & 3));

  // ---- qkva tile assignment ----
  const int qcnt = (cgrp < 4) ? 5 : 4;
  const int qst = (cgrp < 4) ? cgrp * 5 : 20 + (cgrp - 4) * 4;
  const int qtile = qst + w;  // valid if w < qcnt

  // ---- hoisted loop-invariant operands (registers) ----
  short8_v bFr[16];
#pragma unroll
  for (int kc = 0; kc < 16; ++kc) bFr[kc] = Wcat[((cgrp * 8 + w) * 16 + kc) * 64 + lane];
  short8_v bQ[8];
  float bqv = 0.f;
  int n0 = 0;
  if (w < qcnt) {
    n0 = qtile * 16 + (lane & 15);
    bqv = biasq[n0];
#pragma unroll
    for (int kc = 0; kc < 8; ++kc) bQ[kc] = Wq[(qtile * 8 + kc) * 64 + lane];
  }
  // ---- aF double-buffer: preload phase 0's gate A-operands ----
  short8_v aFc[8];
#pragma unroll
  for (int kc = 0; kc < 8; ++kc) aFc[kc] = tswz[(m * 8 + kc) * 64 + lane];

#pragma unroll 1
  for (int p = 0; p <= 129; ++p) {
    const int hrd = (p + 1) & 1, hwr = p & 1;
    const int s = p - 2;  // tape step
    const int par = s & 1;
    short8_v aFn[8];

    // ---- stage h(p-1) into LDS first (critical path to sync1 -> gates) ----
    if (p >= 1 && p <= 128) {
      const unsigned long long* hsrc = (const unsigned long long*)(hG + (size_t)hrd * 131072) +
                                       ((size_t)(m * 8 + w) * 64 + lane) * 2;
      unsigned long long lo = ald(hsrc), hi = ald(hsrc + 1);
      hstage_u64[((size_t)w * 64 + lane) * 2] = lo;
      hstage_u64[((size_t)w * 64 + lane) * 2 + 1] = hi;
    }
    // ---- early issue: tape's qkva-row loads (values needed only post-arrive) ----
    float a_[11];
    f32x4 q4, val4;
    if (s >= 0) {
      const float* qrow = qkva + (size_t)(s & 1) * (512 * QC) + (size_t)b * QC;
#pragma unroll
      for (int j = 0; j < 11; ++j) a_[j] = ald(qrow + 512 + tp * 11 + j);
      unsigned long long u0 = ald((const unsigned long long*)(qrow + tp * 64 + c4 * 4));
      unsigned long long u1 = ald((const unsigned long long*)(qrow + tp * 64 + c4 * 4 + 2));
      unsigned long long v0 = ald((const unsigned long long*)(qrow + 256 + tp * 64 + c4 * 4));
      unsigned long long v1 = ald((const unsigned long long*)(qrow + 256 + tp * 64 + c4 * 4 + 2));
      float2 qa = __builtin_bit_cast(float2, u0), qb = __builtin_bit_cast(float2, u1);
      float2 va = __builtin_bit_cast(float2, v0), vb = __builtin_bit_cast(float2, v1);
      q4 = (f32x4){qa.x, qa.y, qb.x, qb.y};
      val4 = (f32x4){va.x, va.y, vb.x, vb.y};
    }
    __syncthreads();  // hstage ready; prev-phase gbuf/hstage uses complete
    // ---- gates MFMA -> gbuf ----
    if (p < 128) {
      f32x4 acc = {0.f, 0.f, 0.f, 0.f};
#pragma unroll
      for (int kc = 0; kc < 8; ++kc)
        acc = __builtin_amdgcn_mfma_f32_16x16x32_bf16(aFc[kc], bFr[kc], acc, 0, 0, 0);
      if (p > 0) {
#pragma unroll
        for (int kc = 8; kc < 16; ++kc) {
          short8_v a = hstage_s8[(kc - 8) * 64 + lane];
          acc = __builtin_amdgcn_mfma_f32_16x16x32_bf16(a, bFr[kc], acc, 0, 0, 0);
        }
      }
      int cl = w >> 2, gate = w & 3;
#pragma unroll
      for (int r = 0; r < 4; ++r)
        gbuf[((cl * 4 + gate) * 16 + ((lane >> 4) * 4 + r)) * 16 + (lane & 15)] = acc[r];
    }
    __syncthreads();  // gbuf ready
    // ---- LSTM epilogue -> h(p) ----
    if (p < 128) {
      float gi = gbuf[(((ecol >> 4) * 4 + 0) * 16 + erow) * 16 + (ecol & 15)] + bI;
      float gf = gbuf[(((ecol >> 4) * 4 + 1) * 16 + erow) * 16 + (ecol & 15)] + bF;
      float gg = gbuf[(((ecol >> 4) * 4 + 2) * 16 + erow) * 16 + (ecol & 15)] + bG_;
      float go = gbuf[(((ecol >> 4) * 4 + 3) * 16 + erow) * 16 + (ecol & 15)] + bO;
      float cc = sigf(gf) * c_reg + sigf(gi) * tfast(gg);
      c_reg = cc;
      float hh = sigf(go) * tfast(cc);
      __hip_bfloat16 hb16 = __float2bfloat16(hh);
      unsigned own = (unsigned)(*(unsigned short*)&hb16);
      unsigned other = (unsigned)__shfl_xor((int)own, 1) & 0xFFFFu;
      if ((ecol & 1) == 0) {
        unsigned pack = (other << 16) | own;
        ast((unsigned*)(hG + (size_t)hwr * 131072) + hIdx32, pack);
      }
    }
    // ---- qkva MFMA for step p-1 ----
    if (p >= 1 && p <= 128 && w < qcnt) {
      f32x4 qa = {0.f, 0.f, 0.f, 0.f};
#pragma unroll
      for (int kc = 0; kc < 8; ++kc)
        qa = __builtin_amdgcn_mfma_f32_16x16x32_bf16(hstage_s8[kc * 64 + lane], bQ[kc], qa, 0, 0, 0);
      float* qw = qkva + (size_t)((p - 1) & 1) * (512 * QC);
#pragma unroll
      for (int r = 0; r < 4; ++r)
        ast(&qw[(size_t)(16 * m + (lane >> 4) * 4 + r) * QC + n0], qa[r] + bqv);
    }
    // ---- drain stores, arrive at group barrier, THEN prefetch + tape (hides barrier) ----
    asm volatile("s_waitcnt vmcnt(0)" ::: "memory");
    __syncthreads();
    if (tid == 0 && p < 129)
      __hip_atomic_fetch_add(grpbar, 1u, __ATOMIC_RELAXED, __HIP_MEMORY_SCOPE_AGENT);
    // ---- prefetch next phase's aF (read-only, not barrier-gated; hidden under tape) ----
    if (p + 1 < 128) {
      const short8_v* xg = tswz + (size_t)(p + 1) * 16384;
#pragma unroll
      for (int kc = 0; kc < 8; ++kc) aFn[kc] = xg[(m * 8 + kc) * 64 + lane];
    }
    // ---- tape compute for step s ----
    if (s >= 0) {
      float m1 = fmaxf(fmaxf(a_[0], a_[1]), fmaxf(a_[2], a_[3]));
      float e0 = __expf(a_[0] - m1), e1 = __expf(a_[1] - m1), e2 = __expf(a_[2] - m1),
            e3 = __expf(a_[3] - m1);
      float inv = 1.f / (e0 + e1 + e2 + e3);
      float rd0 = e0 * inv, rd1 = e1 * inv, rd2 = e2 * inv, rd3 = e3 * inv;
      float m2 = fmaxf(fmaxf(a_[4], a_[5]), fmaxf(a_[6], a_[7]));
      float f0 = __expf(a_[4] - m2), f1 = __expf(a_[5] - m2), f2 = __expf(a_[6] - m2),
            f3 = __expf(a_[7] - m2);
      float inv2 = 1.f / (f0 + f1 + f2 + f3);
      float wd0 = f0 * inv2, wd1 = f1 * inv2, wd2 = f2 * inv2, wd3 = f3 * inv2;
      float rwe0 = sigf(a_[8]), rwe1 = sigf(a_[9]), rwe2 = sigf(a_[10]);
      // qn: normalize q over 64 cols (lane holds 4 cols; reduce over c4 groups)
      float ss = q4[0] * q4[0] + q4[1] * q4[1] + q4[2] * q4[2] + q4[3] * q4[3];
#pragma unroll
      for (int off = 1; off < 16; off <<= 1) ss += __shfl_xor(ss, off);
      float qninv = 1.f / fmaxf(sqrtf(ss), 1e-12f);
      f32x4 qn4 = q4 * qninv;
      // stage per-row {wp, rs} (lane=row) and qn (g==0 lanes)
      *(float2*)&S[par * 128 + lane * 2] = make_float2(wp, rp * rwe0);
      if (g == 0) *(f32x4*)&S[256 + c4 * 4] = qn4;
      f32x4 dv4 = *(const f32x4*)&S[320 + c4 * 4];  // pending rank-1 (prev phase)
      // row pass: apply pending, write back, reduce oldval & rval
      f32x4 oa = {0.f, 0.f, 0.f, 0.f}, ra = oa;
#pragma unroll
      for (int i = 0; i < 16; ++i) {
        int row = i * 4 + g;
        float2 wrO = *(const float2*)&S[(par ^ 1) * 128 + row * 2];
        float2 wrN = *(const float2*)&S[par * 128 + row * 2];
        int ti = row * 16 + (c4 ^ (row & 15));
        f32x4 v = Tc[ti];
        v += wrO.x * dv4;
        Tc[ti] = v;
        oa += wrN.x * v;
        ra += wrN.y * v;
      }
#pragma unroll
      for (int off = 16; off <= 32; off <<= 1) {
        f32x4 t;
        t[0] = __shfl_xor(oa[0], off); t[1] = __shfl_xor(oa[1], off);
        t[2] = __shfl_xor(oa[2], off); t[3] = __shfl_xor(oa[3], off);
        oa += t;
        t[0] = __shfl_xor(ra[0], off); t[1] = __shfl_xor(ra[1], off);
        t[2] = __shfl_xor(ra[2], off); t[3] = __shfl_xor(ra[3], off);
        ra += t;
      }
      f32x4 dvn = val4 * rwe1 - oa * rwe2;
      if (g == 0) {
        *(f32x4*)&S[320 + c4 * 4] = dvn;  // next phase's pending
        *(f32x4*)(out + (size_t)s * 131072 + b * 256 + tp * 64 + c4 * 4) = ra;
      }
      // col pass: jq[row=lane] = sum_c T[row][c]*qn[c]
      float jq = 0.f;
#pragma unroll
      for (int j = 0; j < 16; ++j) {
        f32x4 v = Tc[lane * 16 + (j ^ (lane & 15))];
        f32x4 qv = *(const f32x4*)&S[256 + j * 4];
        jq += v[0] * qv[0] + v[1] * qv[1] + v[2] * qv[2] + v[3] * qv[3];
      }
      float jsum = wave_sum(jq * jq);
      float jp = jq / fmaxf(sqrtf(jsum), 1e-12f);
      // roll(x,1)[i]=x[i-1] (next_*), roll(x,-1)[i]=x[i+1] (prev_*)
      float next_w = __shfl(wp, (lane + 63) & 63);
      float prev_w = __shfl(wp, (lane + 1) & 63);
      float next_r = __shfl(rp, (lane + 63) & 63);
      float prev_r = __shfl(rp, (lane + 1) & 63);
      wp = prev_w * wd0 + wp * wd1 + next_w * wd2 + jp * wd3;
      rp = prev_r * rd0 + rp * rd1 + next_r * rd2 + jp * rd3;
    }
    // ---- wait for group (tape overlapped most of the skew) ----
    if (p < 129) {
      __syncthreads();
      if (tid == 0) {
        unsigned target = 8u * (unsigned)(p + 1);
        while (ald(grpbar) < target) __builtin_amdgcn_s_sleep(2);
        asm volatile("" ::: "memory");
      }
      __syncthreads();
    }
    // ---- rotate aF double-buffer ----
    if (p + 1 < 128) {
#pragma unroll
      for (int kc = 0; kc < 8; ++kc) aFc[kc] = aFn[kc];
    }
  }
}

// ---------------- host ----------------

extern "C" void kernel_launch(void* const* d_in, const int* in_sizes, int n_in, void* d_out,
                              int out_size, void* d_ws, size_t ws_size, hipStream_t stream) {
  const float* tgt = (const float*)d_in[0];
  const float* src = (const float*)d_in[1];
  const float* W_ih = (const float*)d_in[2];
  const float* W_hh = (const float*)d_in[3];
  const float* b_ih = (const float*)d_in[4];
  const float* b_hh = (const float*)d_in[5];
  const float* Wq_w = (const float*)d_in[6];
  const float* Wq_b = (const float*)d_in[7];
  float* out = (float*)d_out;

  char* ws = (char*)d_ws;
  size_t off = 0;
  auto alloc = [&](size_t bytes) -> void* {
    void* p = ws + off;
    off = (off + bytes + 255) & ~(size_t)255;
    return p;
  };
  unsigned* bars = (unsigned*)alloc(2048 * 4);
  float* qkva = (float*)alloc((size_t)2 * 512 * QC * 4);
  unsigned short* hG = (unsigned short*)alloc((size_t)2 * 131072 * 2);
  __hip_bfloat16* Wcat = (__hip_bfloat16*)alloc((size_t)1024 * 512 * 2);
  __hip_bfloat16* Wq = (__hip_bfloat16*)alloc((size_t)576 * 256 * 2);
  float* biasq = (float*)alloc((size_t)576 * 4);
  __hip_bfloat16* tswz = (__hip_bfloat16*)alloc((size_t)128 * 131072 * 2);

  reset_bars<<<8, 256, 0, stream>>>(bars);
  prep_weights<<<2048, 256, 0, stream>>>(W_ih, W_hh, Wcat);
  prep_wq<<<576, 256, 0, stream>>>(Wq_w, Wq_b, Wq, biasq);
  prep_tgt<<<8192, 256, 0, stream>>>(tgt, tswz);

  hipFuncSetAttribute((const void*)persist, hipFuncAttributeMaxDynamicSharedMemorySize, DYN_LDS);

  const short8_v* tswz_p = (const short8_v*)tswz;
  const short8_v* Wcat_p = (const short8_v*)Wcat;
  const short8_v* Wq_p = (const short8_v*)Wq;
  const float* biasq_p = biasq;
  const float* bih_p = b_ih;
  const float* bhh_p = b_hh;
  unsigned short* hG_p = hG;
  float* qkva_p = qkva;
  float* out_p = out;
  const float* src_p = src;
  unsigned* bars_p = bars;
  void* kargs[] = {(void*)&tswz_p, (void*)&Wcat_p, (void*)&Wq_p,  (void*)&biasq_p,
                   (void*)&bih_p,  (void*)&bhh_p,  (void*)&hG_p,  (void*)&qkva_p,
                   (void*)&out_p,  (void*)&src_p,  (void*)&bars_p};
  hipLaunchCooperativeKernel((const void*)persist, dim3(256), dim3(512), kargs,
                             (unsigned)DYN_LDS, stream);
}